// Round 1
// baseline (516.340 us; speedup 1.0000x reference)
//
#include <hip/hip_runtime.h>
#include <hip/hip_bf16.h>
#include <math.h>

#define B 4
#define C 256
#define T 8
#define H 128
#define WW 64
#define IC 128
#define S 64          // t*STRIPE tokens
#define NSTRIPE 8
#define HS 16
#define REGION 1024   // HS*WW contiguous floats per stripe region
#define EPS 1e-5f

// ---------------- K1: stripe mean pool ----------------
// grid = B*C*T*NSTRIPE = 65536 blocks, 256 threads.
// Block sb covers x[sb*1024 .. sb*1024+1024); sb is also the flat (b,c,s)
// index into dn (since stripe is the fastest-varying dim and s = t*8+stripe).
__global__ void pool_kernel(const float* __restrict__ x, float* __restrict__ dn) {
    int sb = blockIdx.x;
    const float4* xr = (const float4*)(x + (size_t)sb * REGION);
    float4 v = xr[threadIdx.x];
    float sum = v.x + v.y + v.z + v.w;
    #pragma unroll
    for (int off = 32; off > 0; off >>= 1)
        sum += __shfl_down(sum, off, 64);
    __shared__ float ws[4];
    int wid = threadIdx.x >> 6;
    int lane = threadIdx.x & 63;
    if (lane == 0) ws[wid] = sum;
    __syncthreads();
    if (threadIdx.x == 0) {
        float tot = ws[0] + ws[1] + ws[2] + ws[3];
        dn[sb] = tot * (1.0f / (float)REGION);
    }
}

// ---------------- K2: g/theta/phi projections ----------------
// grid = B*S = 256 blocks, 128 threads. Thread i computes g/th/ph[b,s,i].
__global__ void proj_kernel(const float* __restrict__ dn,
                            const float* __restrict__ gw, const float* __restrict__ gb,
                            const float* __restrict__ tw, const float* __restrict__ tb,
                            const float* __restrict__ pw, const float* __restrict__ pb,
                            float* __restrict__ g, float* __restrict__ th,
                            float* __restrict__ ph) {
    int blk = blockIdx.x;
    int b = blk >> 6, s = blk & 63;
    __shared__ float dloc[C];
    for (int ch = threadIdx.x; ch < C; ch += blockDim.x)
        dloc[ch] = dn[(b * C + ch) * S + s];
    __syncthreads();
    int i = threadIdx.x;  // 0..127
    float ag = gb[i], at = tb[i], ap = pb[i];
    const float* gwr = gw + i * C;
    const float* twr = tw + i * C;
    const float* pwr = pw + i * C;
    for (int ch = 0; ch < C; ++ch) {
        float d = dloc[ch];
        ag = fmaf(d, gwr[ch], ag);
        at = fmaf(d, twr[ch], at);
        ap = fmaf(d, pwr[ch], ap);
    }
    size_t o = ((size_t)(b * S + s)) * IC + i;
    g[o] = ag; th[o] = at; ph[o] = ap;
}

// ---------------- K3: attention (scores + softmax + P·g) ----------------
// grid = B*S = 256 blocks, 128 threads. Wave 0 (lanes 0..63) computes the
// 64 scores for token s and the softmax via cross-lane shuffles; then all
// 128 threads compute y[b,s,i] with coalesced g reads.
__global__ void attn_kernel(const float* __restrict__ g,
                            const float* __restrict__ th,
                            const float* __restrict__ ph,
                            float* __restrict__ y) {
    int blk = blockIdx.x;
    int b = blk >> 6, s = blk & 63;
    __shared__ float p[S];
    __shared__ float thloc[IC];
    int tid = threadIdx.x;
    thloc[tid] = th[((size_t)(b * S + s)) * IC + tid];
    __syncthreads();
    if (tid < 64) {
        int r = tid;
        const float* phr = ph + ((size_t)(b * S + r)) * IC;
        float f = 0.0f;
        for (int i = 0; i < IC; ++i) f = fmaf(thloc[i], phr[i], f);
        float m = f;
        #pragma unroll
        for (int off = 32; off > 0; off >>= 1)
            m = fmaxf(m, __shfl_xor(m, off, 64));
        float e = __expf(f - m);
        float sum = e;
        #pragma unroll
        for (int off = 32; off > 0; off >>= 1)
            sum += __shfl_xor(sum, off, 64);
        p[r] = e / sum;
    }
    __syncthreads();
    int i = tid;  // 0..127
    float acc = 0.0f;
    for (int r = 0; r < S; ++r)
        acc = fmaf(p[r], g[((size_t)(b * S + r)) * IC + i], acc);
    y[((size_t)(b * S + s)) * IC + i] = acc;
}

// ---------------- K4: output projection + BatchNorm (eval) ----------------
// 65536 threads; thread -> (b, ch, s); writes wy flat in (b,c,S) order.
__global__ void outproj_kernel(const float* __restrict__ y,
                               const float* __restrict__ Ww, const float* __restrict__ Wb,
                               const float* __restrict__ gamma, const float* __restrict__ beta,
                               const float* __restrict__ mean, const float* __restrict__ var,
                               float* __restrict__ wy) {
    int idx = blockIdx.x * blockDim.x + threadIdx.x;
    int s = idx & 63;
    int ch = (idx >> 6) & 255;
    int b = idx >> 14;
    const float* yr = y + ((size_t)(b * S + s)) * IC;
    const float* wr = Ww + (size_t)ch * IC;
    float acc = Wb[ch];
    for (int i = 0; i < IC; ++i) acc = fmaf(yr[i], wr[i], acc);
    float inv = gamma[ch] * rsqrtf(var[ch] + EPS);
    wy[idx] = (acc - mean[ch]) * inv + beta[ch];
}

// ---------------- K5: broadcast residual add ----------------
// One float4 per thread; 256 consecutive float4s share one wy value.
__global__ void add_kernel(const float* __restrict__ x,
                           const float* __restrict__ wy,
                           float* __restrict__ out) {
    size_t f = (size_t)blockIdx.x * blockDim.x + threadIdx.x;
    const float4* x4 = (const float4*)x;
    float4* o4 = (float4*)out;
    float4 v = x4[f];
    float a = wy[f >> 8];
    v.x += a; v.y += a; v.z += a; v.w += a;
    o4[f] = v;
}

extern "C" void kernel_launch(void* const* d_in, const int* in_sizes, int n_in,
                              void* d_out, int out_size, void* d_ws, size_t ws_size,
                              hipStream_t stream) {
    const float* x       = (const float*)d_in[0];
    const float* g_w     = (const float*)d_in[1];
    const float* g_b     = (const float*)d_in[2];
    const float* theta_w = (const float*)d_in[3];
    const float* theta_b = (const float*)d_in[4];
    const float* phi_w   = (const float*)d_in[5];
    const float* phi_b   = (const float*)d_in[6];
    const float* W_w     = (const float*)d_in[7];
    const float* W_b     = (const float*)d_in[8];
    const float* bn_g    = (const float*)d_in[9];
    const float* bn_b    = (const float*)d_in[10];
    const float* bn_m    = (const float*)d_in[11];
    const float* bn_v    = (const float*)d_in[12];
    float* out = (float*)d_out;

    // workspace layout (floats)
    float* ws = (float*)d_ws;
    float* dn = ws;                  // B*C*S      = 65536
    float* g  = dn + B * C * S;      // B*S*IC     = 32768
    float* th = g  + B * S * IC;     // 32768
    float* ph = th + B * S * IC;     // 32768
    float* y  = ph + B * S * IC;     // 32768
    float* wy = y  + B * S * IC;     // B*C*S      = 65536

    const int nRegions = B * C * T * NSTRIPE;          // 65536
    pool_kernel<<<nRegions, 256, 0, stream>>>(x, dn);

    proj_kernel<<<B * S, IC, 0, stream>>>(dn, g_w, g_b, theta_w, theta_b,
                                          phi_w, phi_b, g, th, ph);

    attn_kernel<<<B * S, IC, 0, stream>>>(g, th, ph, y);

    outproj_kernel<<<(B * C * S) / 256, 256, 0, stream>>>(y, W_w, W_b,
                                                          bn_g, bn_b, bn_m, bn_v, wy);

    const size_t nVec4 = (size_t)B * C * T * H * WW / 4;  // 16777216
    add_kernel<<<(int)(nVec4 / 256), 256, 0, stream>>>(x, wy, out);
}